// Round 4
// baseline (472.398 us; speedup 1.0000x reference)
//
#include <hip/hip_runtime.h>
#include <hip/hip_bf16.h>
#include <math.h>

// Fused conv3x3(64->64) + bias + min_k + tanh(tanh()) via bf16 MFMA implicit GEMM.
// x: [16,64,256,256] f32, w: [64,64,3,3] f32, b: [64] f32, out: [16,1,256,256] f32
//
// Round 10: persistent blocks + double-buffered LDS 2-phase pipeline.
//   r9 post-mortem: compiler sank the "in-flight" stage loads (VGPR 84 proved it);
//   stage->barrier->compute stays serial; >50% of cycles unattributed stall.
//   This round (T3 minimum-2-phase + T14 issue-early/write-late, from the GEMM
//   ladder):
//   - 512 persistent blocks (exactly 2/CU), each owns 8 w-adjacent 16x16 tiles
//     = 16 chunk-steps (tile k 0..7 x c-chunk kc 0..1).
//   - Per step: issue loads(step s+1) -> sched_barrier(0) [pin: no sinking] ->
//     compute step s from sA[cur] (144 MFMA hides the load latency) ->
//     epilogue if kc==1 -> sched_barrier(0) [pin: no hoisting of vmcnt-wait] ->
//     cvt + ds_write into sA[cur^1] -> ONE __syncthreads -> flip.
//   - LDS: 2 x 28.8 KB = 57.6 KB (2 blocks/CU). __launch_bounds__(256,2):
//     256-reg cap; peak live ~190 (acc 64 + prefetch 64 + frags 32 + addr).
//   - XCD map: xcd=g&7 owns 2 whole images; halo cols L1-hot (w-sweep), halo
//     rows same-XCD L2-hot.
//   - KEPT: B-frags from global wB (L2-hot, r8-verified), SA_PX=40 pad
//     (<=2-way LDS aliasing), verified epilogue.
// mfma_f32_16x16x32_bf16: A[m=lane&15][k=(lane>>4)*8+j], B[k=(lane>>4)*8+j][n=lane&15],
//                         C/D col=lane&15, row=(lane>>4)*4+reg (HW-verified r2-r9).

typedef __bf16 bf16x8 __attribute__((ext_vector_type(8)));
typedef float f32x4 __attribute__((ext_vector_type(4)));

#define WB_ELEMS (64 * 64 * 9)
#define SA_PX   40                      // elements per pixel slot (32 used + 8 pad)
#define SA_ROW  (20 * SA_PX)            // 800 elements per row (20 px)
#define SA_ELEMS (18 * SA_ROW)          // 14400 elems = 28800 B per buffer

// ---- weight prep: w[k][c][tap] -> wB[(((chunk*9+tap)*4+nt)*64+lane)*8+j] ----
__global__ __launch_bounds__(256)
void conv_prep_w(const float* __restrict__ w, __bf16* __restrict__ wB) {
    int idx = blockIdx.x * 256 + threadIdx.x;
    if (idx >= WB_ELEMS) return;
    int k   = idx / 576;
    int rem = idx - k * 576;
    int c   = rem / 9;
    int tap = rem - c * 9;
    int nt = k >> 4, m15 = k & 15;
    int chunk = c >> 5, q = (c >> 3) & 3, j = c & 7;
    int lane = (q << 4) | m15;
    wB[((((chunk * 9 + tap) * 4 + nt) * 64 + lane) << 3) + j] = (__bf16)w[idx];
}

// ---- fused persistent kernel ----
__global__ __launch_bounds__(256, 2)
void conv_min_tanh_fused(const float* __restrict__ x,
                         const __bf16* __restrict__ wB,
                         const float* __restrict__ b,
                         float* __restrict__ out)
{
    __shared__ __attribute__((aligned(16))) __bf16 sA[2][SA_ELEMS];  // 57600 B

    const int tid  = threadIdx.x;
    const int lane = tid & 63;
    const int wave = tid >> 6;
    const int m15  = lane & 15;
    const int q    = lane >> 4;

    // persistent-block tile mapping: 512 blocks, 8 tiles each.
    // xcd = g&7 -> images {xcd, xcd+8}; within image: 16 h-rows x 2 w-halves;
    // block sweeps 8 consecutive w-tiles (k=0..7).
    const int g      = blockIdx.x;
    const int i      = g >> 3;
    const int n      = (g & 7) + ((i >> 5) << 3);
    const int jj     = i & 31;
    const int h0     = (jj >> 1) << 4;
    const int w0base = (jj & 1) << 7;

    // staging slot decomposition (constant per thread across steps)
    // slot = row*20 + span*4 + cg ; slot covers 4 px (span) x 8 c (cg*8..+7)
    const int slot0 = tid;
    const int row0 = slot0 / 20, rem0 = slot0 - row0 * 20;
    const int span0 = rem0 >> 2, cg0 = rem0 & 3;
    const int slot1 = tid + 256;
    const bool has1 = slot1 < 360;               // tid < 104
    const int row1 = slot1 / 20, rem1 = slot1 - row1 * 20;
    const int span1 = rem1 >> 2, cg1 = rem1 & 3;

    auto load_one = [&](int row, int span, int cg, int k, int kc, f32x4 v[8]) {
        const int gh  = h0 + row - 1;
        const int gw0 = w0base + (k << 4) - 1 + span * 4;
        if ((unsigned)gh < 256u) {
            const float* src = x + (size_t)(n * 64 + kc * 32 + cg * 8) * 65536
                                 + (size_t)gh * 256;
            if (gw0 >= 0 && gw0 <= 252) {
#pragma unroll
                for (int j = 0; j < 8; ++j)
                    v[j] = *(const f32x4*)&src[(size_t)j * 65536 + gw0];
            } else {
#pragma unroll
                for (int j = 0; j < 8; ++j)
#pragma unroll
                    for (int ii = 0; ii < 4; ++ii) {
                        const int gw = gw0 + ii;
                        v[j][ii] = ((unsigned)gw < 256u) ? src[(size_t)j * 65536 + gw] : 0.f;
                    }
            }
        } else {
#pragma unroll
            for (int j = 0; j < 8; ++j)
                v[j] = (f32x4){0.f, 0.f, 0.f, 0.f};
        }
    };
    auto write_one = [&](int row, int span, int cg, const f32x4 v[8], __bf16* dst) {
        __bf16* wp = dst + row * SA_ROW + (span * 4) * SA_PX + cg * 8;
#pragma unroll
        for (int ii = 0; ii < 4; ++ii) {
            bf16x8 o;
            o[0] = (__bf16)v[0][ii]; o[1] = (__bf16)v[1][ii];
            o[2] = (__bf16)v[2][ii]; o[3] = (__bf16)v[3][ii];
            o[4] = (__bf16)v[4][ii]; o[5] = (__bf16)v[5][ii];
            o[6] = (__bf16)v[6][ii]; o[7] = (__bf16)v[7][ii];
            *(bf16x8*)&wp[ii * SA_PX] = o;
        }
    };

    float bias[4];
#pragma unroll
    for (int nt = 0; nt < 4; ++nt) bias[nt] = b[nt * 16 + m15];

    f32x4 pv0[8], pv1[8];
    f32x4 acc[4][4];

    // ---- prologue: stage step 0 into sA[0] ----
    load_one(row0, span0, cg0, 0, 0, pv0);
    if (has1) load_one(row1, span1, cg1, 0, 0, pv1);
    write_one(row0, span0, cg0, pv0, sA[0]);
    if (has1) write_one(row1, span1, cg1, pv1, sA[0]);
    __syncthreads();

    int cur = 0;
#pragma unroll 1
    for (int s = 0; s < 16; ++s) {
        const int k  = s >> 1;
        const int kc = s & 1;

        if (kc == 0) {
#pragma unroll
            for (int mt = 0; mt < 4; ++mt)
#pragma unroll
                for (int nt = 0; nt < 4; ++nt)
                    acc[mt][nt] = (f32x4){0.f, 0.f, 0.f, 0.f};
        }

        // ---- issue next step's loads (stay in regs through the compute) ----
        if (s < 15) {
            const int k1  = (s + 1) >> 1;
            const int kc1 = (s + 1) & 1;
            load_one(row0, span0, cg0, k1, kc1, pv0);
            if (has1) load_one(row1, span1, cg1, k1, kc1, pv1);
        }
        __builtin_amdgcn_sched_barrier(0);   // pin: loads must not sink past compute

        // ---- compute step s from sA[cur]; B-frags from global (L2-hot) ----
        const __bf16* sAc = sA[cur];
        const __bf16* wBc = wB + kc * 18432;
#pragma unroll
        for (int r = 0; r < 3; ++r) {
#pragma unroll
            for (int s2 = 0; s2 < 3; ++s2) {
                const int tap = r * 3 + s2;
                bf16x8 bf4[4], a4[4];
#pragma unroll
                for (int nt = 0; nt < 4; ++nt)
                    bf4[nt] = *(const bf16x8*)&wBc[(((tap << 2) | nt) << 9) | (lane << 3)];
#pragma unroll
                for (int mt = 0; mt < 4; ++mt)
                    a4[mt] = *(const bf16x8*)
                        &sAc[(wave * 4 + mt + r) * SA_ROW + (m15 + s2) * SA_PX + q * 8];
#pragma unroll
                for (int mt = 0; mt < 4; ++mt)
#pragma unroll
                    for (int nt = 0; nt < 4; ++nt)
                        acc[mt][nt] = __builtin_amdgcn_mfma_f32_16x16x32_bf16(
                            a4[mt], bf4[nt], acc[mt][nt], 0, 0, 0);
            }
        }

        // ---- epilogue at tile end (overlaps other block's work) ----
        if (kc == 1) {
            const int w0 = w0base + (k << 4);
#pragma unroll
            for (int mt = 0; mt < 4; ++mt) {
                float mv[4];
#pragma unroll
                for (int reg = 0; reg < 4; ++reg) {
                    float v2 = acc[mt][0][reg] + bias[0];
                    v2 = fminf(v2, acc[mt][1][reg] + bias[1]);
                    v2 = fminf(v2, acc[mt][2][reg] + bias[2]);
                    v2 = fminf(v2, acc[mt][3][reg] + bias[3]);
                    v2 = fminf(v2, __shfl_xor(v2, 1));
                    v2 = fminf(v2, __shfl_xor(v2, 2));
                    v2 = fminf(v2, __shfl_xor(v2, 4));
                    v2 = fminf(v2, __shfl_xor(v2, 8));
                    mv[reg] = v2;
                }
                const int r2 = lane & 3;
                float v2 = mv[0];
                v2 = (r2 == 1) ? mv[1] : v2;
                v2 = (r2 == 2) ? mv[2] : v2;
                v2 = (r2 == 3) ? mv[3] : v2;
                v2 = tanhf(tanhf(v2));
                if (m15 < 4) {
                    const int gh = h0 + wave * 4 + mt;
                    const int gw = w0 + q * 4 + r2;
                    out[((size_t)n * 256 + gh) * 256 + gw] = v2;
                }
            }
        }

        __builtin_amdgcn_sched_barrier(0);   // pin: writes (vmcnt wait) stay after MFMAs

        // ---- write prefetched step s+1 into the other buffer ----
        if (s < 15) {
            write_one(row0, span0, cg0, pv0, sA[cur ^ 1]);
            if (has1) write_one(row1, span1, cg1, pv1, sA[cur ^ 1]);
        }
        __syncthreads();
        cur ^= 1;
    }
}

extern "C" void kernel_launch(void* const* d_in, const int* in_sizes, int n_in,
                              void* d_out, int out_size, void* d_ws, size_t ws_size,
                              hipStream_t stream) {
    const float* x = (const float*)d_in[0];
    const float* w = (const float*)d_in[1];
    const float* b = (const float*)d_in[2];
    float* out = (float*)d_out;
    __bf16* wB = (__bf16*)d_ws;  // 73728 B

    conv_prep_w<<<dim3(144), dim3(256), 0, stream>>>(w, wB);
    conv_min_tanh_fused<<<dim3(512), dim3(256), 0, stream>>>(x, wB, b, out);
}